// Round 4
// baseline (556.410 us; speedup 1.0000x reference)
//
#include <hip/hip_runtime.h>

#define V_N   100000
#define E_N   300000
#define IN_C  256
#define OUT_C 256
#define NREL2 474
#define BN_EPS 1e-5f
#define MTILES 782            // ceil(V_N/128)

typedef __attribute__((ext_vector_type(8))) short short8;
typedef __attribute__((ext_vector_type(4))) float f32x4;

__device__ __forceinline__ unsigned short f2bf(float f) {
    unsigned int u = __builtin_bit_cast(unsigned int, f);
    u += 0x7FFFu + ((u >> 16) & 1u);          // RNE
    return (unsigned short)(u >> 16);
}

typedef const __attribute__((address_space(1))) unsigned int* gas1_t;
typedef __attribute__((address_space(3))) unsigned int* las3_t;
__device__ __forceinline__ void gload16(const void* g, void* l) {
    __builtin_amdgcn_global_load_lds((gas1_t)g, (las3_t)l, 16, 0, 0);
}

// ---------------- CSR build ----------------

__global__ void count_kernel(const int* __restrict__ dst, int* __restrict__ cnt) {
    int e = blockIdx.x * 256 + threadIdx.x;
    if (e < E_N) atomicAdd(&cnt[dst[e]], 1);
}

// single block: fused inv-sqrt degree + exclusive scan of cnt -> offs
__global__ __launch_bounds__(1024)
void scan_all(const int* __restrict__ cnt, int* __restrict__ offs,
              float* __restrict__ degi) {
    __shared__ int ssum[1024];
    const int t = threadIdx.x;
    const int v0 = t * 98;
    const int v1 = (v0 + 98 < V_N) ? v0 + 98 : V_N;
    int s = 0;
    for (int v = v0; v < v1; ++v) {
        int c = cnt[v];
        s += c;
        degi[v] = c > 0 ? rsqrtf((float)c) : 0.f;
    }
    ssum[t] = s;
    __syncthreads();
    for (int d = 1; d < 1024; d <<= 1) {
        int add = (t >= d) ? ssum[t - d] : 0;
        __syncthreads();
        ssum[t] += add;
        __syncthreads();
    }
    int run = (t > 0) ? ssum[t - 1] : 0;
    for (int v = v0; v < v1; ++v) {
        offs[v] = run;
        run += cnt[v];
    }
}

__global__ void scatter_kernel(const int* __restrict__ dst, const int* __restrict__ src,
                               const int* __restrict__ etype, const int* __restrict__ edir,
                               const int* __restrict__ offs, int* __restrict__ cursor,
                               int* __restrict__ epack) {
    int e = blockIdx.x * 256 + threadIdx.x;
    if (e < E_N) {
        int d = dst[e];
        int pos = offs[d] + atomicAdd(&cursor[d], 1);
        epack[pos] = src[e] | (etype[e] << 17) | (edir[e] << 26);
    }
}

// WcT[n][k] = bf16(w_flat[k][n]); rows k>=512 pre-multiplied by loop_rel[k-512]
__global__ void convert_w(const float* __restrict__ w, const float* __restrict__ loop_rel,
                          unsigned short* __restrict__ WcT) {
    int k = blockIdx.x;    // 0..767
    int n = threadIdx.x;   // 0..255
    float f = w[(size_t)k * 256 + n];
    if (k >= 512) f *= loop_rel[k - 512];
    WcT[(size_t)n * 768 + k] = f2bf(f);
}

// ---------------- aggregate: one wave per dst node ----------------
// Apre[v][0..255]=dir0 agg, [256..511]=dir1 agg (bf16).
// Also emits xbf = bf16(x[v]) tile-locally into d_out scratch:
//   outu + (v>>7)*65536 + (v&127)*256 + c   (ushort units)
__global__ __launch_bounds__(256)
void aggregate(const float* __restrict__ x, const float* __restrict__ rel_repr,
               const float* __restrict__ degi,
               const int* __restrict__ cnt, const int* __restrict__ offs,
               const int* __restrict__ epack, unsigned short* __restrict__ Apre,
               unsigned short* __restrict__ outu) {
    int wid = (blockIdx.x * 256 + threadIdx.x) >> 6;
    int lane = threadIdx.x & 63;
    if (wid >= V_N) return;
    const int v = wid;
    const int n = cnt[v];
    const int base = offs[v];
    const float dv = degi[v];
    const int c4 = lane * 4;
    float4 a0 = make_float4(0.f, 0.f, 0.f, 0.f);
    float4 a1 = make_float4(0.f, 0.f, 0.f, 0.f);
    int i = 0;
    for (; i + 2 <= n; i += 2) {
        int p0 = epack[base + i];
        int p1 = epack[base + i + 1];
        int s0 = p0 & 0x1FFFF, s1 = p1 & 0x1FFFF;
        int e0 = (p0 >> 17) & 0x1FF, e1 = (p1 >> 17) & 0x1FF;
        float en0 = degi[s0] * dv, en1 = degi[s1] * dv;
        float4 xv0 = *(const float4*)(x + (size_t)s0 * IN_C + c4);
        float4 rv0 = *(const float4*)(rel_repr + (size_t)e0 * IN_C + c4);
        float4 xv1 = *(const float4*)(x + (size_t)s1 * IN_C + c4);
        float4 rv1 = *(const float4*)(rel_repr + (size_t)e1 * IN_C + c4);
        float4 m0, m1;
        m0.x = xv0.x * rv0.x * en0; m0.y = xv0.y * rv0.y * en0;
        m0.z = xv0.z * rv0.z * en0; m0.w = xv0.w * rv0.w * en0;
        m1.x = xv1.x * rv1.x * en1; m1.y = xv1.y * rv1.y * en1;
        m1.z = xv1.z * rv1.z * en1; m1.w = xv1.w * rv1.w * en1;
        if (p0 & (1 << 26)) { a1.x += m0.x; a1.y += m0.y; a1.z += m0.z; a1.w += m0.w; }
        else                { a0.x += m0.x; a0.y += m0.y; a0.z += m0.z; a0.w += m0.w; }
        if (p1 & (1 << 26)) { a1.x += m1.x; a1.y += m1.y; a1.z += m1.z; a1.w += m1.w; }
        else                { a0.x += m1.x; a0.y += m1.y; a0.z += m1.z; a0.w += m1.w; }
    }
    if (i < n) {
        int p  = epack[base + i];
        int s  = p & 0x1FFFF;
        int et = (p >> 17) & 0x1FF;
        float en = degi[s] * dv;
        float4 xv = *(const float4*)(x + (size_t)s * IN_C + c4);
        float4 rv = *(const float4*)(rel_repr + (size_t)et * IN_C + c4);
        float4 m;
        m.x = xv.x * rv.x * en; m.y = xv.y * rv.y * en;
        m.z = xv.z * rv.z * en; m.w = xv.w * rv.w * en;
        if (p & (1 << 26)) { a1.x += m.x; a1.y += m.y; a1.z += m.z; a1.w += m.w; }
        else               { a0.x += m.x; a0.y += m.y; a0.z += m.z; a0.w += m.w; }
    }
    ushort4 u0, u1;
    u0.x = f2bf(a0.x); u0.y = f2bf(a0.y); u0.z = f2bf(a0.z); u0.w = f2bf(a0.w);
    u1.x = f2bf(a1.x); u1.y = f2bf(a1.y); u1.z = f2bf(a1.z); u1.w = f2bf(a1.w);
    *(ushort4*)(Apre + (size_t)v * 512 + c4)       = u0;
    *(ushort4*)(Apre + (size_t)v * 512 + 256 + c4) = u1;
    // xbf (self-loop A operand; loop_rel folded into WcT)
    float4 xv = *(const float4*)(x + (size_t)v * IN_C + c4);
    ushort4 ux;
    ux.x = f2bf(xv.x); ux.y = f2bf(xv.y); ux.z = f2bf(xv.z); ux.w = f2bf(xv.w);
    *(ushort4*)(outu + (size_t)(v >> 7) * 65536 + (size_t)(v & 127) * 256 + c4) = ux;
}

// ---------------- fused GEMM, 2-deep counted-vmcnt pipeline ----------------
// out_h(bf16, into Apre rows) = [Apre | xbf] @ WcT^T, /3 + bias; BN col partials.
// 128 rows x 256 cols per block, 8 waves (2x4). K=768, BK=64, 12 steps.
// LDS: A dbuf 2x16KB @0, B dbuf 2x32KB @32768 (96KB). Epilogue reuses LDS.
__global__ __launch_bounds__(512)
void mfma_gemm(unsigned short* Ap /* Apre, also h output */,
               const unsigned short* __restrict__ xbf,
               const unsigned short* __restrict__ WcT,
               const float* __restrict__ bias, float* __restrict__ partial) {
    __shared__ __align__(16) unsigned char smem[98304];

    const int t    = threadIdx.x;
    const int m0   = blockIdx.x * 128;
    const int wid  = t >> 6;
    const int lane = t & 63;
    const int wm   = wid >> 2;
    const int wn   = wid & 3;
    const int lr   = lane & 15;
    const int qk   = lane >> 4;
    const int sxr  = lr & 7;
    const int wbase = t & 0x1C0;

    // staging constants
    int arow[2], acsw[2], brow[4], bcsw[4];
    #pragma unroll
    for (int j = 0; j < 2; ++j) {
        int g = j * 512 + t;
        arow[j] = g >> 3;
        acsw[j] = (g & 7) ^ (arow[j] & 7);
    }
    #pragma unroll
    for (int j = 0; j < 4; ++j) {
        int g = j * 512 + t;
        brow[j] = g >> 3;
        bcsw[j] = (g & 7) ^ (brow[j] & 7);
    }

    auto A_lds = [&](int buf) { return (unsigned short*)(smem + buf * 16384); };
    auto B_lds = [&](int buf) { return (unsigned short*)(smem + 32768 + buf * 32768); };

    auto stage = [&](int buf, int ks) {
        #pragma unroll
        for (int j = 0; j < 2; ++j) {
            int rg = m0 + arow[j];
            if (rg >= V_N) rg = V_N - 1;
            const unsigned short* s = (ks < 8)
                ? Ap  + (size_t)rg * 512 + ks * 64 + acsw[j] * 8
                : xbf + (size_t)blockIdx.x * 65536 + (size_t)(rg - m0) * 256 + (ks - 8) * 64 + acsw[j] * 8;
            gload16(s, A_lds(buf) + (size_t)(j * 512 + wbase) * 8);
        }
        #pragma unroll
        for (int j = 0; j < 4; ++j) {
            const unsigned short* s = WcT + (size_t)brow[j] * 768 + ks * 64 + bcsw[j] * 8;
            gload16(s, B_lds(buf) + (size_t)(j * 512 + wbase) * 8);
        }
    };

    f32x4 acc[4][4];
    #pragma unroll
    for (int m = 0; m < 4; m++)
        #pragma unroll
        for (int n = 0; n < 4; n++)
            acc[m][n] = (f32x4){0.f, 0.f, 0.f, 0.f};

    stage(0, 0);
    stage(1, 1);

    #pragma unroll
    for (int ks = 0; ks < 12; ++ks) {
        const int buf = ks & 1;
        if (ks < 11) { asm volatile("s_waitcnt vmcnt(6)" ::: "memory"); }
        else         { asm volatile("s_waitcnt vmcnt(0)" ::: "memory"); }
        __builtin_amdgcn_s_barrier();
        __builtin_amdgcn_sched_barrier(0);
        const unsigned short* Ab = A_lds(buf);
        const unsigned short* Bb = B_lds(buf);
        #pragma unroll
        for (int h = 0; h < 2; ++h) {
            short8 av[4], bv[4];
            #pragma unroll
            for (int m = 0; m < 4; m++)
                av[m] = *(const short8*)&Ab[(size_t)((wm * 64 + m * 16 + lr) * 8 + ((h * 4 + qk) ^ sxr)) * 8];
            #pragma unroll
            for (int n = 0; n < 4; n++)
                bv[n] = *(const short8*)&Bb[(size_t)((wn * 64 + n * 16 + lr) * 8 + ((h * 4 + qk) ^ sxr)) * 8];
            #pragma unroll
            for (int m = 0; m < 4; m++)
                #pragma unroll
                for (int n = 0; n < 4; n++)
                    acc[m][n] = __builtin_amdgcn_mfma_f32_16x16x32_bf16(av[m], bv[n], acc[m][n], 0, 0, 0);
        }
        __builtin_amdgcn_sched_barrier(0);
        __builtin_amdgcn_s_barrier();
        __builtin_amdgcn_sched_barrier(0);
        if (ks + 2 < 12) stage(buf, ks + 2);
    }

    // ---- epilogue: h = acc/3 + bias (bf16), LDS-staged coalesced store, BN partials ----
    unsigned short* Cst = (unsigned short*)smem;     // [64][264] ushort = 33792 B
    float* bs = (float*)(smem + 34816);              // 512 floats
    bs[t] = 0.f;
    __syncthreads();

    const float inv3 = 1.f / 3.f;
    float bco[4];
    #pragma unroll
    for (int n = 0; n < 4; n++) bco[n] = bias[wn * 64 + n * 16 + lr];

    float s[4]  = {0.f, 0.f, 0.f, 0.f};
    float s2[4] = {0.f, 0.f, 0.f, 0.f};

    #pragma unroll
    for (int p = 0; p < 2; ++p) {
        if (wm == p) {
            #pragma unroll
            for (int m = 0; m < 4; m++) {
                #pragma unroll
                for (int n = 0; n < 4; n++) {
                    const int col = wn * 64 + n * 16 + lr;
                    #pragma unroll
                    for (int j = 0; j < 4; j++) {
                        int rl = m * 16 + qk * 4 + j;
                        float h = acc[m][n][j] * inv3 + bco[n];
                        if (m0 + p * 64 + rl < V_N) { s[n] += h; s2[n] += h * h; }
                        Cst[rl * 264 + col] = f2bf(h);
                    }
                }
            }
        }
        __syncthreads();
        #pragma unroll
        for (int i = 0; i < 4; ++i) {
            int f = t + i * 512;            // 0..2047 chunks of 8 ushorts
            int row = f >> 5;
            int c8  = (f & 31) * 8;
            int r = m0 + p * 64 + row;
            if (r < V_N) {
                uint4 val = *(const uint4*)&Cst[row * 264 + c8];
                *(uint4*)&Ap[(size_t)r * 512 + c8] = val;
            }
        }
        __syncthreads();
    }

    #pragma unroll
    for (int n = 0; n < 4; n++) {
        s[n]  += __shfl_xor(s[n], 16);  s[n]  += __shfl_xor(s[n], 32);
        s2[n] += __shfl_xor(s2[n], 16); s2[n] += __shfl_xor(s2[n], 32);
    }
    if (lane < 16) {
        #pragma unroll
        for (int n = 0; n < 4; n++) {
            const int col = wn * 64 + n * 16 + lr;
            atomicAdd(&bs[col], s[n]);
            atomicAdd(&bs[256 + col], s2[n]);
        }
    }
    __syncthreads();
    partial[(size_t)blockIdx.x * 512 + t] = bs[t];
}

// ---------------- BN reduce + finalize + normalize ----------------

__global__ void bn_reduce_part(const float* __restrict__ partial, float* __restrict__ sums) {
    int t = threadIdx.x;                       // 512
    int b0 = blockIdx.x * 196;
    int b1 = b0 + 196; if (b1 > MTILES) b1 = MTILES;
    float S = 0.f;
    for (int b = b0; b < b1; b++) S += partial[(size_t)b * 512 + t];
    atomicAdd(&sums[t], S);
}

__global__ void bn_finalize(const float* __restrict__ sums, float* __restrict__ ms) {
    int c = threadIdx.x;                       // 256
    float mean = sums[c] / (float)V_N;
    float var  = sums[256 + c] / (float)V_N - mean * mean;
    ms[c]       = mean;
    ms[256 + c] = rsqrtf(var + BN_EPS);
}

// read h (bf16, Apre rows), write normalized f32 out
__global__ void bn_norm2(const unsigned short* __restrict__ hbf,
                         const float* __restrict__ ms, float* __restrict__ out) {
    const size_t total8 = (size_t)V_N * 32;    // chunks of 8 elems
    size_t stride = (size_t)gridDim.x * blockDim.x;
    for (size_t idx = (size_t)blockIdx.x * blockDim.x + threadIdx.x; idx < total8; idx += stride) {
        size_t v  = idx >> 5;
        int   c8  = (int)(idx & 31) * 8;
        uint4 uv = *(const uint4*)&hbf[v * 512 + c8];
        float4 ma = *(const float4*)&ms[c8];
        float4 mb = *(const float4*)&ms[c8 + 4];
        float4 ra = *(const float4*)&ms[256 + c8];
        float4 rb = *(const float4*)&ms[256 + c8 + 4];
        unsigned int w0 = uv.x, w1 = uv.y, w2 = uv.z, w3 = uv.w;
        float4 h0, h1;
        h0.x = (__builtin_bit_cast(float, (w0 << 16))        - ma.x) * ra.x;
        h0.y = (__builtin_bit_cast(float, (w0 & 0xFFFF0000u)) - ma.y) * ra.y;
        h0.z = (__builtin_bit_cast(float, (w1 << 16))        - ma.z) * ra.z;
        h0.w = (__builtin_bit_cast(float, (w1 & 0xFFFF0000u)) - ma.w) * ra.w;
        h1.x = (__builtin_bit_cast(float, (w2 << 16))        - mb.x) * rb.x;
        h1.y = (__builtin_bit_cast(float, (w2 & 0xFFFF0000u)) - mb.y) * rb.y;
        h1.z = (__builtin_bit_cast(float, (w3 << 16))        - mb.z) * rb.z;
        h1.w = (__builtin_bit_cast(float, (w3 & 0xFFFF0000u)) - mb.w) * rb.w;
        float* o = out + v * 256 + c8;
        *(float4*)o       = h0;
        *(float4*)(o + 4) = h1;
    }
}

__global__ void rel_out_kernel(const float* __restrict__ rel_repr,
                               const float* __restrict__ loop_rel,
                               const float* __restrict__ w_rel,
                               float* __restrict__ out)
{
    int r = blockIdx.x;
    const float* row = (r < NREL2) ? (rel_repr + (size_t)r * IN_C) : loop_rel;
    int l = threadIdx.x;
    float s = 0.f;
    #pragma unroll
    for (int q = 0; q < 4; q++) {
        int k = l + q * 64;
        s += row[k] * w_rel[(size_t)k * OUT_C + (OUT_C - 1)];
    }
    #pragma unroll
    for (int m = 32; m >= 1; m >>= 1) s += __shfl_xor(s, m);
    if (l == 0) out[(size_t)V_N * OUT_C + r] = s;
}

// ---------------- launch ----------------

extern "C" void kernel_launch(void* const* d_in, const int* in_sizes, int n_in,
                              void* d_out, int out_size, void* d_ws, size_t ws_size,
                              hipStream_t stream) {
    const float* x        = (const float*)d_in[0];
    const float* rel_repr = (const float*)d_in[1];
    const float* w        = (const float*)d_in[2];
    const float* w_rel    = (const float*)d_in[3];
    const float* loop_rel = (const float*)d_in[4];
    const float* bias     = (const float*)d_in[5];
    const int*   src      = (const int*)d_in[6];
    const int*   dst      = (const int*)d_in[7];
    const int*   etype    = (const int*)d_in[8];
    const int*   edir     = (const int*)d_in[9];
    float* out = (float*)d_out;
    unsigned short* outu = (unsigned short*)d_out;

    // workspace layout (105.60 MB, within round-2-proven bound)
    char* wsb = (char*)d_ws;
    int*   cnt     = (int*)(wsb + 0);              // 400,000
    int*   cursor  = (int*)(wsb + 400000);         // 400,000
    int*   offs    = (int*)(wsb + 800000);         // 400,000
    float* degi    = (float*)(wsb + 1200000);      // 400,000
    float* partial = (float*)(wsb + 0);            // alias region0 (1,601,536 < 1,601,792)
    int*   epack   = (int*)(wsb + 1601792);        // 1,200,000
    float* ms      = (float*)(wsb + 2801792);      // 2048
    float* sums    = (float*)(wsb + 2803840);      // 2048
    unsigned short* WcT  = (unsigned short*)(wsb + 2805888);   // 393,216
    unsigned short* Apre = (unsigned short*)(wsb + 3199104);   // 102,400,000

    hipMemsetAsync(wsb, 0, 800000, stream);        // cnt + cursor
    hipMemsetAsync(sums, 0, 2048, stream);

    count_kernel<<<(E_N + 255) / 256, 256, 0, stream>>>(dst, cnt);
    scan_all<<<1, 1024, 0, stream>>>(cnt, offs, degi);
    scatter_kernel<<<(E_N + 255) / 256, 256, 0, stream>>>(dst, src, etype, edir,
                                                          offs, cursor, epack);
    convert_w<<<768, 256, 0, stream>>>(w, loop_rel, WcT);
    aggregate<<<(V_N + 3) / 4, 256, 0, stream>>>(x, rel_repr, degi, cnt, offs, epack,
                                                 Apre, outu);
    mfma_gemm<<<MTILES, 512, 0, stream>>>(Apre, outu, WcT, bias, partial);
    bn_reduce_part<<<4, 512, 0, stream>>>(partial, sums);
    bn_finalize<<<1, 256, 0, stream>>>(sums, ms);
    bn_norm2<<<2048, 256, 0, stream>>>(Apre, ms, out);
    rel_out_kernel<<<NREL2 + 1, 64, 0, stream>>>(rel_repr, loop_rel, w_rel, out);
}

// Round 5
// 296.066 us; speedup vs baseline: 1.8793x; 1.8793x over previous
//
#include <hip/hip_runtime.h>

#define V_N   100000
#define E_N   300000
#define IN_C  256
#define OUT_C 256
#define NREL2 474
#define BN_EPS 1e-5f
#define NB_SCAN 98            // ceil(V_N/1024)
#define MTILES 782            // ceil(V_N/128)

typedef __attribute__((ext_vector_type(8))) short short8;
typedef __attribute__((ext_vector_type(4))) float f32x4;

__device__ __forceinline__ unsigned short f2bf(float f) {
    unsigned int u = __builtin_bit_cast(unsigned int, f);
    u += 0x7FFFu + ((u >> 16) & 1u);          // RNE
    return (unsigned short)(u >> 16);
}

typedef const __attribute__((address_space(1))) unsigned int* gas1_t;
typedef __attribute__((address_space(3))) unsigned int* las3_t;
__device__ __forceinline__ void gload16(const void* g, void* l) {
    __builtin_amdgcn_global_load_lds((gas1_t)g, (las3_t)l, 16, 0, 0);
}

// ---------------- CSR build ----------------

__global__ void count_kernel(const int* __restrict__ dst, int* __restrict__ cnt) {
    int e = blockIdx.x * 256 + threadIdx.x;
    if (e < E_N) atomicAdd(&cnt[dst[e]], 1);
}

// coalesced per-block sums; also emits degi = rsqrt(cnt)
__global__ __launch_bounds__(1024)
void scan1(const int* __restrict__ cnt, int* __restrict__ bsum, float* __restrict__ degi) {
    __shared__ int red[1024];
    int t = threadIdx.x;
    int v = blockIdx.x * 1024 + t;
    int c = (v < V_N) ? cnt[v] : 0;
    if (v < V_N) degi[v] = c > 0 ? rsqrtf((float)c) : 0.f;
    red[t] = c;
    __syncthreads();
    for (int s = 512; s > 0; s >>= 1) {
        if (t < s) red[t] += red[t + s];
        __syncthreads();
    }
    if (t == 0) bsum[blockIdx.x] = red[0];
}

__global__ void scan2(int* bsum) {
    if (threadIdx.x == 0) {
        int run = 0;
        for (int i = 0; i < NB_SCAN; i++) { int tv = bsum[i]; bsum[i] = run; run += tv; }
    }
}

__global__ __launch_bounds__(1024)
void scan3(const int* __restrict__ cnt, const int* __restrict__ bsum,
           int* __restrict__ offs) {
    __shared__ int sc[1024];
    int t = threadIdx.x;
    int v = blockIdx.x * 1024 + t;
    int c = (v < V_N) ? cnt[v] : 0;
    sc[t] = c;
    __syncthreads();
    for (int d = 1; d < 1024; d <<= 1) {
        int add = (t >= d) ? sc[t - d] : 0;
        __syncthreads();
        sc[t] += add;
        __syncthreads();
    }
    if (v < V_N) offs[v] = sc[t] - c + bsum[blockIdx.x];
}

__global__ void scatter_kernel(const int* __restrict__ dst, const int* __restrict__ src,
                               const int* __restrict__ etype, const int* __restrict__ edir,
                               const int* __restrict__ offs, int* __restrict__ cursor,
                               int* __restrict__ epack) {
    int e = blockIdx.x * 256 + threadIdx.x;
    if (e < E_N) {
        int d = dst[e];
        int pos = offs[d] + atomicAdd(&cursor[d], 1);
        epack[pos] = src[e] | (etype[e] << 17) | (edir[e] << 26);
    }
}

// WcT[n][k] = bf16(w_flat[k][n]); rows k>=512 pre-multiplied by loop_rel[k-512]
__global__ void convert_w(const float* __restrict__ w, const float* __restrict__ loop_rel,
                          unsigned short* __restrict__ WcT) {
    int k = blockIdx.x;    // 0..767
    int n = threadIdx.x;   // 0..255
    float f = w[(size_t)k * 256 + n];
    if (k >= 512) f *= loop_rel[k - 512];
    WcT[(size_t)n * 768 + k] = f2bf(f);
}

// ---------------- aggregate: one wave per dst node ----------------
// Apre[v][0..255]=dir0 agg, [256..511]=dir1 agg (bf16).
// Also emits xbf = bf16(x[v]) tile-locally into d_out scratch:
//   outu + (v>>7)*65536 + (v&127)*256 + c   (ushort units)
__global__ __launch_bounds__(256)
void aggregate(const float* __restrict__ x, const float* __restrict__ rel_repr,
               const float* __restrict__ degi,
               const int* __restrict__ cnt, const int* __restrict__ offs,
               const int* __restrict__ epack, unsigned short* __restrict__ Apre,
               unsigned short* __restrict__ outu) {
    int wid = (blockIdx.x * 256 + threadIdx.x) >> 6;
    int lane = threadIdx.x & 63;
    if (wid >= V_N) return;
    const int v = wid;
    const int n = cnt[v];
    const int base = offs[v];
    const float dv = degi[v];
    const int c4 = lane * 4;
    float4 a0 = make_float4(0.f, 0.f, 0.f, 0.f);
    float4 a1 = make_float4(0.f, 0.f, 0.f, 0.f);
    int i = 0;
    for (; i + 2 <= n; i += 2) {
        int p0 = epack[base + i];
        int p1 = epack[base + i + 1];
        int s0 = p0 & 0x1FFFF, s1 = p1 & 0x1FFFF;
        int e0 = (p0 >> 17) & 0x1FF, e1 = (p1 >> 17) & 0x1FF;
        float en0 = degi[s0] * dv, en1 = degi[s1] * dv;
        float4 xv0 = *(const float4*)(x + (size_t)s0 * IN_C + c4);
        float4 rv0 = *(const float4*)(rel_repr + (size_t)e0 * IN_C + c4);
        float4 xv1 = *(const float4*)(x + (size_t)s1 * IN_C + c4);
        float4 rv1 = *(const float4*)(rel_repr + (size_t)e1 * IN_C + c4);
        float4 m0, m1;
        m0.x = xv0.x * rv0.x * en0; m0.y = xv0.y * rv0.y * en0;
        m0.z = xv0.z * rv0.z * en0; m0.w = xv0.w * rv0.w * en0;
        m1.x = xv1.x * rv1.x * en1; m1.y = xv1.y * rv1.y * en1;
        m1.z = xv1.z * rv1.z * en1; m1.w = xv1.w * rv1.w * en1;
        if (p0 & (1 << 26)) { a1.x += m0.x; a1.y += m0.y; a1.z += m0.z; a1.w += m0.w; }
        else                { a0.x += m0.x; a0.y += m0.y; a0.z += m0.z; a0.w += m0.w; }
        if (p1 & (1 << 26)) { a1.x += m1.x; a1.y += m1.y; a1.z += m1.z; a1.w += m1.w; }
        else                { a0.x += m1.x; a0.y += m1.y; a0.z += m1.z; a0.w += m1.w; }
    }
    if (i < n) {
        int p  = epack[base + i];
        int s  = p & 0x1FFFF;
        int et = (p >> 17) & 0x1FF;
        float en = degi[s] * dv;
        float4 xv = *(const float4*)(x + (size_t)s * IN_C + c4);
        float4 rv = *(const float4*)(rel_repr + (size_t)et * IN_C + c4);
        float4 m;
        m.x = xv.x * rv.x * en; m.y = xv.y * rv.y * en;
        m.z = xv.z * rv.z * en; m.w = xv.w * rv.w * en;
        if (p & (1 << 26)) { a1.x += m.x; a1.y += m.y; a1.z += m.z; a1.w += m.w; }
        else               { a0.x += m.x; a0.y += m.y; a0.z += m.z; a0.w += m.w; }
    }
    ushort4 u0, u1;
    u0.x = f2bf(a0.x); u0.y = f2bf(a0.y); u0.z = f2bf(a0.z); u0.w = f2bf(a0.w);
    u1.x = f2bf(a1.x); u1.y = f2bf(a1.y); u1.z = f2bf(a1.z); u1.w = f2bf(a1.w);
    *(ushort4*)(Apre + (size_t)v * 512 + c4)       = u0;
    *(ushort4*)(Apre + (size_t)v * 512 + 256 + c4) = u1;
    // xbf (self-loop A operand; loop_rel folded into WcT)
    float4 xv = *(const float4*)(x + (size_t)v * IN_C + c4);
    ushort4 ux;
    ux.x = f2bf(xv.x); ux.y = f2bf(xv.y); ux.z = f2bf(xv.z); ux.w = f2bf(xv.w);
    *(ushort4*)(outu + (size_t)(v >> 7) * 65536 + (size_t)(v & 127) * 256 + c4) = ux;
}

// ---------------- fused GEMM, 2-deep counted-vmcnt pipeline ----------------
// out_h(bf16, into Apre rows) = [Apre | xbf] @ WcT^T, /3 + bias; BN col partials.
// 128 rows x 256 cols per block, 8 waves (2x4). K=768, BK=64, 12 steps.
// LDS: A dbuf 2x16KB @0, B dbuf 2x32KB @32768 (96KB). Epilogue reuses LDS.
__global__ __launch_bounds__(512)
void mfma_gemm(unsigned short* Ap /* Apre, also h output */,
               const unsigned short* __restrict__ xbf,
               const unsigned short* __restrict__ WcT,
               const float* __restrict__ bias, float* __restrict__ partial) {
    __shared__ __align__(16) unsigned char smem[98304];

    const int t    = threadIdx.x;
    const int m0   = blockIdx.x * 128;
    const int wid  = t >> 6;
    const int lane = t & 63;
    const int wm   = wid >> 2;
    const int wn   = wid & 3;
    const int lr   = lane & 15;
    const int qk   = lane >> 4;
    const int sxr  = lr & 7;
    const int wbase = t & 0x1C0;

    // staging constants
    int arow[2], acsw[2], brow[4], bcsw[4];
    #pragma unroll
    for (int j = 0; j < 2; ++j) {
        int g = j * 512 + t;
        arow[j] = g >> 3;
        acsw[j] = (g & 7) ^ (arow[j] & 7);
    }
    #pragma unroll
    for (int j = 0; j < 4; ++j) {
        int g = j * 512 + t;
        brow[j] = g >> 3;
        bcsw[j] = (g & 7) ^ (brow[j] & 7);
    }

    auto A_lds = [&](int buf) { return (unsigned short*)(smem + buf * 16384); };
    auto B_lds = [&](int buf) { return (unsigned short*)(smem + 32768 + buf * 32768); };

    auto stage = [&](int buf, int ks) {
        #pragma unroll
        for (int j = 0; j < 2; ++j) {
            int rg = m0 + arow[j];
            if (rg >= V_N) rg = V_N - 1;
            const unsigned short* s = (ks < 8)
                ? Ap  + (size_t)rg * 512 + ks * 64 + acsw[j] * 8
                : xbf + (size_t)blockIdx.x * 65536 + (size_t)(rg - m0) * 256 + (ks - 8) * 64 + acsw[j] * 8;
            gload16(s, A_lds(buf) + (size_t)(j * 512 + wbase) * 8);
        }
        #pragma unroll
        for (int j = 0; j < 4; ++j) {
            const unsigned short* s = WcT + (size_t)brow[j] * 768 + ks * 64 + bcsw[j] * 8;
            gload16(s, B_lds(buf) + (size_t)(j * 512 + wbase) * 8);
        }
    };

    f32x4 acc[4][4];
    #pragma unroll
    for (int m = 0; m < 4; m++)
        #pragma unroll
        for (int n = 0; n < 4; n++)
            acc[m][n] = (f32x4){0.f, 0.f, 0.f, 0.f};

    stage(0, 0);
    stage(1, 1);

    #pragma unroll
    for (int ks = 0; ks < 12; ++ks) {
        const int buf = ks & 1;
        if (ks < 11) { asm volatile("s_waitcnt vmcnt(6)" ::: "memory"); }
        else         { asm volatile("s_waitcnt vmcnt(0)" ::: "memory"); }
        __builtin_amdgcn_s_barrier();
        __builtin_amdgcn_sched_barrier(0);
        const unsigned short* Ab = A_lds(buf);
        const unsigned short* Bb = B_lds(buf);
        #pragma unroll
        for (int h = 0; h < 2; ++h) {
            short8 av[4], bv[4];
            #pragma unroll
            for (int m = 0; m < 4; m++)
                av[m] = *(const short8*)&Ab[(size_t)((wm * 64 + m * 16 + lr) * 8 + ((h * 4 + qk) ^ sxr)) * 8];
            #pragma unroll
            for (int n = 0; n < 4; n++)
                bv[n] = *(const short8*)&Bb[(size_t)((wn * 64 + n * 16 + lr) * 8 + ((h * 4 + qk) ^ sxr)) * 8];
            #pragma unroll
            for (int m = 0; m < 4; m++)
                #pragma unroll
                for (int n = 0; n < 4; n++)
                    acc[m][n] = __builtin_amdgcn_mfma_f32_16x16x32_bf16(av[m], bv[n], acc[m][n], 0, 0, 0);
        }
        __builtin_amdgcn_sched_barrier(0);
        __builtin_amdgcn_s_barrier();
        __builtin_amdgcn_sched_barrier(0);
        if (ks + 2 < 12) stage(buf, ks + 2);
    }

    // ---- epilogue: h = acc/3 + bias (bf16), LDS-staged coalesced store, BN partials ----
    unsigned short* Cst = (unsigned short*)smem;     // [64][264] ushort = 33792 B
    float* bs = (float*)(smem + 34816);              // 512 floats
    bs[t] = 0.f;
    __syncthreads();

    const float inv3 = 1.f / 3.f;
    float bco[4];
    #pragma unroll
    for (int n = 0; n < 4; n++) bco[n] = bias[wn * 64 + n * 16 + lr];

    float s[4]  = {0.f, 0.f, 0.f, 0.f};
    float s2[4] = {0.f, 0.f, 0.f, 0.f};

    #pragma unroll
    for (int p = 0; p < 2; ++p) {
        if (wm == p) {
            #pragma unroll
            for (int m = 0; m < 4; m++) {
                #pragma unroll
                for (int n = 0; n < 4; n++) {
                    const int col = wn * 64 + n * 16 + lr;
                    #pragma unroll
                    for (int j = 0; j < 4; j++) {
                        int rl = m * 16 + qk * 4 + j;
                        float h = acc[m][n][j] * inv3 + bco[n];
                        if (m0 + p * 64 + rl < V_N) { s[n] += h; s2[n] += h * h; }
                        Cst[rl * 264 + col] = f2bf(h);
                    }
                }
            }
        }
        __syncthreads();
        #pragma unroll
        for (int i = 0; i < 4; ++i) {
            int f = t + i * 512;            // 0..2047 chunks of 8 ushorts
            int row = f >> 5;
            int c8  = (f & 31) * 8;
            int r = m0 + p * 64 + row;
            if (r < V_N) {
                uint4 val = *(const uint4*)&Cst[row * 264 + c8];
                *(uint4*)&Ap[(size_t)r * 512 + c8] = val;
            }
        }
        __syncthreads();
    }

    #pragma unroll
    for (int n = 0; n < 4; n++) {
        s[n]  += __shfl_xor(s[n], 16);  s[n]  += __shfl_xor(s[n], 32);
        s2[n] += __shfl_xor(s2[n], 16); s2[n] += __shfl_xor(s2[n], 32);
    }
    if (lane < 16) {
        #pragma unroll
        for (int n = 0; n < 4; n++) {
            const int col = wn * 64 + n * 16 + lr;
            atomicAdd(&bs[col], s[n]);
            atomicAdd(&bs[256 + col], s2[n]);
        }
    }
    __syncthreads();
    partial[(size_t)blockIdx.x * 512 + t] = bs[t];
}

// ---------------- BN reduce + finalize + normalize ----------------

__global__ void bn_reduce_part(const float* __restrict__ partial, float* __restrict__ sums) {
    int t = threadIdx.x;                       // 512
    int b0 = blockIdx.x * 196;
    int b1 = b0 + 196; if (b1 > MTILES) b1 = MTILES;
    float S = 0.f;
    for (int b = b0; b < b1; b++) S += partial[(size_t)b * 512 + t];
    atomicAdd(&sums[t], S);
}

__global__ void bn_finalize(const float* __restrict__ sums, float* __restrict__ ms) {
    int c = threadIdx.x;                       // 256
    float mean = sums[c] / (float)V_N;
    float var  = sums[256 + c] / (float)V_N - mean * mean;
    ms[c]       = mean;
    ms[256 + c] = rsqrtf(var + BN_EPS);
}

// read h (bf16, Apre rows), write normalized f32 out
__global__ void bn_norm2(const unsigned short* __restrict__ hbf,
                         const float* __restrict__ ms, float* __restrict__ out) {
    const size_t total8 = (size_t)V_N * 32;    // chunks of 8 elems
    size_t stride = (size_t)gridDim.x * blockDim.x;
    for (size_t idx = (size_t)blockIdx.x * blockDim.x + threadIdx.x; idx < total8; idx += stride) {
        size_t v  = idx >> 5;
        int   c8  = (int)(idx & 31) * 8;
        uint4 uv = *(const uint4*)&hbf[v * 512 + c8];
        float4 ma = *(const float4*)&ms[c8];
        float4 mb = *(const float4*)&ms[c8 + 4];
        float4 ra = *(const float4*)&ms[256 + c8];
        float4 rb = *(const float4*)&ms[256 + c8 + 4];
        unsigned int w0 = uv.x, w1 = uv.y, w2 = uv.z, w3 = uv.w;
        float4 h0, h1;
        h0.x = (__builtin_bit_cast(float, (w0 << 16))        - ma.x) * ra.x;
        h0.y = (__builtin_bit_cast(float, (w0 & 0xFFFF0000u)) - ma.y) * ra.y;
        h0.z = (__builtin_bit_cast(float, (w1 << 16))        - ma.z) * ra.z;
        h0.w = (__builtin_bit_cast(float, (w1 & 0xFFFF0000u)) - ma.w) * ra.w;
        h1.x = (__builtin_bit_cast(float, (w2 << 16))        - mb.x) * rb.x;
        h1.y = (__builtin_bit_cast(float, (w2 & 0xFFFF0000u)) - mb.y) * rb.y;
        h1.z = (__builtin_bit_cast(float, (w3 << 16))        - mb.z) * rb.z;
        h1.w = (__builtin_bit_cast(float, (w3 & 0xFFFF0000u)) - mb.w) * rb.w;
        float* o = out + v * 256 + c8;
        *(float4*)o       = h0;
        *(float4*)(o + 4) = h1;
    }
}

__global__ void rel_out_kernel(const float* __restrict__ rel_repr,
                               const float* __restrict__ loop_rel,
                               const float* __restrict__ w_rel,
                               float* __restrict__ out)
{
    int r = blockIdx.x;
    const float* row = (r < NREL2) ? (rel_repr + (size_t)r * IN_C) : loop_rel;
    int l = threadIdx.x;
    float s = 0.f;
    #pragma unroll
    for (int q = 0; q < 4; q++) {
        int k = l + q * 64;
        s += row[k] * w_rel[(size_t)k * OUT_C + (OUT_C - 1)];
    }
    #pragma unroll
    for (int m = 32; m >= 1; m >>= 1) s += __shfl_xor(s, m);
    if (l == 0) out[(size_t)V_N * OUT_C + r] = s;
}

// ---------------- launch ----------------

extern "C" void kernel_launch(void* const* d_in, const int* in_sizes, int n_in,
                              void* d_out, int out_size, void* d_ws, size_t ws_size,
                              hipStream_t stream) {
    const float* x        = (const float*)d_in[0];
    const float* rel_repr = (const float*)d_in[1];
    const float* w        = (const float*)d_in[2];
    const float* w_rel    = (const float*)d_in[3];
    const float* loop_rel = (const float*)d_in[4];
    const float* bias     = (const float*)d_in[5];
    const int*   src      = (const int*)d_in[6];
    const int*   dst      = (const int*)d_in[7];
    const int*   etype    = (const int*)d_in[8];
    const int*   edir     = (const int*)d_in[9];
    float* out = (float*)d_out;
    unsigned short* outu = (unsigned short*)d_out;

    // workspace layout (105.60 MB, within round-2-proven bound)
    char* wsb = (char*)d_ws;
    int*   cnt     = (int*)(wsb + 0);              // 400,000
    int*   cursor  = (int*)(wsb + 400000);         // 400,000
    int*   offs    = (int*)(wsb + 800000);         // 400,000
    float* degi    = (float*)(wsb + 1200000);      // 400,000
    int*   bsum    = (int*)(wsb + 1600000);        // 392
    float* partial = (float*)(wsb + 0);            // alias region0 (1,601,536 < 1,601,792)
    int*   epack   = (int*)(wsb + 1601792);        // 1,200,000
    float* ms      = (float*)(wsb + 2801792);      // 2048
    float* sums    = (float*)(wsb + 2803840);      // 2048
    unsigned short* WcT  = (unsigned short*)(wsb + 2805888);   // 393,216
    unsigned short* Apre = (unsigned short*)(wsb + 3199104);   // 102,400,000

    hipMemsetAsync(wsb, 0, 800000, stream);        // cnt + cursor
    hipMemsetAsync(sums, 0, 2048, stream);

    count_kernel<<<(E_N + 255) / 256, 256, 0, stream>>>(dst, cnt);
    scan1<<<NB_SCAN, 1024, 0, stream>>>(cnt, bsum, degi);
    scan2<<<1, 64, 0, stream>>>(bsum);
    scan3<<<NB_SCAN, 1024, 0, stream>>>(cnt, bsum, offs);
    scatter_kernel<<<(E_N + 255) / 256, 256, 0, stream>>>(dst, src, etype, edir,
                                                          offs, cursor, epack);
    convert_w<<<768, 256, 0, stream>>>(w, loop_rel, WcT);
    aggregate<<<(V_N + 3) / 4, 256, 0, stream>>>(x, rel_repr, degi, cnt, offs, epack,
                                                 Apre, outu);
    mfma_gemm<<<MTILES, 512, 0, stream>>>(Apre, outu, WcT, bias, partial);
    bn_reduce_part<<<4, 512, 0, stream>>>(partial, sums);
    bn_finalize<<<1, 256, 0, stream>>>(sums, ms);
    bn_norm2<<<2048, 256, 0, stream>>>(Apre, ms, out);
    rel_out_kernel<<<NREL2 + 1, 64, 0, stream>>>(rel_repr, loop_rel, w_rel, out);
}

// Round 6
// 292.560 us; speedup vs baseline: 1.9019x; 1.0120x over previous
//
#include <hip/hip_runtime.h>

#define V_N   100000
#define E_N   300000
#define IN_C  256
#define OUT_C 256
#define NREL2 474
#define BN_EPS 1e-5f
#define NB_SCAN 98            // ceil(V_N/1024)
#define MTILES 782            // ceil(V_N/128)

typedef __attribute__((ext_vector_type(8))) short short8;
typedef __attribute__((ext_vector_type(4))) float f32x4;

__device__ __forceinline__ unsigned short f2bf(float f) {
    unsigned int u = __builtin_bit_cast(unsigned int, f);
    u += 0x7FFFu + ((u >> 16) & 1u);          // RNE
    return (unsigned short)(u >> 16);
}
__device__ __forceinline__ unsigned int pk2bf(float lo, float hi) {
    return (unsigned int)f2bf(lo) | ((unsigned int)f2bf(hi) << 16);
}

typedef const __attribute__((address_space(1))) unsigned int* gas1_t;
typedef __attribute__((address_space(3))) unsigned int* las3_t;
__device__ __forceinline__ void gload16(const void* g, void* l) {
    __builtin_amdgcn_global_load_lds((gas1_t)g, (las3_t)l, 16, 0, 0);
}

// ---------------- CSR build ----------------

__global__ void count_kernel(const int* __restrict__ dst, int* __restrict__ cnt) {
    int e = blockIdx.x * 256 + threadIdx.x;
    if (e < E_N) atomicAdd(&cnt[dst[e]], 1);
}

// coalesced per-block sums; also emits degi = rsqrt(cnt)
__global__ __launch_bounds__(1024)
void scan1(const int* __restrict__ cnt, int* __restrict__ bsum, float* __restrict__ degi) {
    __shared__ int red[1024];
    int t = threadIdx.x;
    int v = blockIdx.x * 1024 + t;
    int c = (v < V_N) ? cnt[v] : 0;
    if (v < V_N) degi[v] = c > 0 ? rsqrtf((float)c) : 0.f;
    red[t] = c;
    __syncthreads();
    for (int s = 512; s > 0; s >>= 1) {
        if (t < s) red[t] += red[t + s];
        __syncthreads();
    }
    if (t == 0) bsum[blockIdx.x] = red[0];
}

// parallel exclusive scan of the 98 block sums (one 128-thread block)
__global__ void scan2(int* bsum) {
    __shared__ int sc[128];
    int t = threadIdx.x;
    int v = (t < NB_SCAN) ? bsum[t] : 0;
    sc[t] = v;
    __syncthreads();
    for (int d = 1; d < 128; d <<= 1) {
        int add = (t >= d) ? sc[t - d] : 0;
        __syncthreads();
        sc[t] += add;
        __syncthreads();
    }
    if (t < NB_SCAN) bsum[t] = sc[t] - v;   // exclusive
}

__global__ __launch_bounds__(1024)
void scan3(const int* __restrict__ cnt, const int* __restrict__ bsum,
           int* __restrict__ offs) {
    __shared__ int sc[1024];
    int t = threadIdx.x;
    int v = blockIdx.x * 1024 + t;
    int c = (v < V_N) ? cnt[v] : 0;
    sc[t] = c;
    __syncthreads();
    for (int d = 1; d < 1024; d <<= 1) {
        int add = (t >= d) ? sc[t - d] : 0;
        __syncthreads();
        sc[t] += add;
        __syncthreads();
    }
    if (v < V_N) offs[v] = sc[t] - c + bsum[blockIdx.x];
}

__global__ void scatter_kernel(const int* __restrict__ dst, const int* __restrict__ src,
                               const int* __restrict__ etype, const int* __restrict__ edir,
                               const int* __restrict__ offs, int* __restrict__ cursor,
                               int* __restrict__ epack) {
    int e = blockIdx.x * 256 + threadIdx.x;
    if (e < E_N) {
        int d = dst[e];
        int pos = offs[d] + atomicAdd(&cursor[d], 1);
        epack[pos] = src[e] | (etype[e] << 17) | (edir[e] << 26);
    }
}

// WcT[n][k] = bf16(w_flat[k][n]); rows k>=512 pre-multiplied by loop_rel[k-512]
__global__ void convert_w(const float* __restrict__ w, const float* __restrict__ loop_rel,
                          unsigned short* __restrict__ WcT) {
    int k = blockIdx.x;    // 0..767
    int n = threadIdx.x;   // 0..255
    float f = w[(size_t)k * 256 + n];
    if (k >= 512) f *= loop_rel[k - 512];
    WcT[(size_t)n * 768 + k] = f2bf(f);
}

// ---------------- aggregate: HALF-WAVE (32 lanes) per dst node ----------------
// 2 nodes per wave + 2-edge unroll = 4 independent gather chains in flight.
// Apre[v][0..255]=dir0 agg, [256..511]=dir1 agg (bf16).
// Also emits xbf = bf16(x[v]) tile-locally: outu + (v>>7)*65536 + (v&127)*256 + c.
__global__ __launch_bounds__(256)
void aggregate(const float* __restrict__ x, const float* __restrict__ rel_repr,
               const float* __restrict__ degi,
               const int* __restrict__ cnt, const int* __restrict__ offs,
               const int* __restrict__ epack, unsigned short* __restrict__ Apre,
               unsigned short* __restrict__ outu) {
    const int node = (blockIdx.x * 256 + threadIdx.x) >> 5;
    const int lane = threadIdx.x & 31;
    if (node >= V_N) return;
    const int v = node;
    const int n = cnt[v];
    const int base = offs[v];
    const float dv = degi[v];
    const int c8 = lane * 8;                 // this lane owns 8 floats of the row

    float4 a0l = {0,0,0,0}, a0h = {0,0,0,0};
    float4 a1l = {0,0,0,0}, a1h = {0,0,0,0};

    int i = 0;
    for (; i + 2 <= n; i += 2) {
        int p0 = epack[base + i];
        int p1 = epack[base + i + 1];
        int s0 = p0 & 0x1FFFF, s1 = p1 & 0x1FFFF;
        int t0 = (p0 >> 17) & 0x1FF, t1 = (p1 >> 17) & 0x1FF;
        float en0 = degi[s0] * dv, en1 = degi[s1] * dv;
        float e00 = (p0 & (1 << 26)) ? 0.f : en0, e01 = en0 - e00;
        float e10 = (p1 & (1 << 26)) ? 0.f : en1, e11 = en1 - e10;
        const float* xr0 = x + (size_t)s0 * IN_C + c8;
        const float* rr0 = rel_repr + (size_t)t0 * IN_C + c8;
        const float* xr1 = x + (size_t)s1 * IN_C + c8;
        const float* rr1 = rel_repr + (size_t)t1 * IN_C + c8;
        float4 xa0 = *(const float4*)xr0, xb0 = *(const float4*)(xr0 + 4);
        float4 ra0 = *(const float4*)rr0, rb0 = *(const float4*)(rr0 + 4);
        float4 xa1 = *(const float4*)xr1, xb1 = *(const float4*)(xr1 + 4);
        float4 ra1 = *(const float4*)rr1, rb1 = *(const float4*)(rr1 + 4);
        float4 ma, mb;
        ma.x = xa0.x * ra0.x; ma.y = xa0.y * ra0.y; ma.z = xa0.z * ra0.z; ma.w = xa0.w * ra0.w;
        mb.x = xb0.x * rb0.x; mb.y = xb0.y * rb0.y; mb.z = xb0.z * rb0.z; mb.w = xb0.w * rb0.w;
        a0l.x += ma.x * e00; a0l.y += ma.y * e00; a0l.z += ma.z * e00; a0l.w += ma.w * e00;
        a0h.x += mb.x * e00; a0h.y += mb.y * e00; a0h.z += mb.z * e00; a0h.w += mb.w * e00;
        a1l.x += ma.x * e01; a1l.y += ma.y * e01; a1l.z += ma.z * e01; a1l.w += ma.w * e01;
        a1h.x += mb.x * e01; a1h.y += mb.y * e01; a1h.z += mb.z * e01; a1h.w += mb.w * e01;
        ma.x = xa1.x * ra1.x; ma.y = xa1.y * ra1.y; ma.z = xa1.z * ra1.z; ma.w = xa1.w * ra1.w;
        mb.x = xb1.x * rb1.x; mb.y = xb1.y * rb1.y; mb.z = xb1.z * rb1.z; mb.w = xb1.w * rb1.w;
        a0l.x += ma.x * e10; a0l.y += ma.y * e10; a0l.z += ma.z * e10; a0l.w += ma.w * e10;
        a0h.x += mb.x * e10; a0h.y += mb.y * e10; a0h.z += mb.z * e10; a0h.w += mb.w * e10;
        a1l.x += ma.x * e11; a1l.y += ma.y * e11; a1l.z += ma.z * e11; a1l.w += ma.w * e11;
        a1h.x += mb.x * e11; a1h.y += mb.y * e11; a1h.z += mb.z * e11; a1h.w += mb.w * e11;
    }
    if (i < n) {
        int p = epack[base + i];
        int s = p & 0x1FFFF;
        int tt = (p >> 17) & 0x1FF;
        float en = degi[s] * dv;
        float e0 = (p & (1 << 26)) ? 0.f : en, e1 = en - e0;
        const float* xr = x + (size_t)s * IN_C + c8;
        const float* rr = rel_repr + (size_t)tt * IN_C + c8;
        float4 xa = *(const float4*)xr, xb = *(const float4*)(xr + 4);
        float4 ra = *(const float4*)rr, rb = *(const float4*)(rr + 4);
        float4 ma, mb;
        ma.x = xa.x * ra.x; ma.y = xa.y * ra.y; ma.z = xa.z * ra.z; ma.w = xa.w * ra.w;
        mb.x = xb.x * rb.x; mb.y = xb.y * rb.y; mb.z = xb.z * rb.z; mb.w = xb.w * rb.w;
        a0l.x += ma.x * e0; a0l.y += ma.y * e0; a0l.z += ma.z * e0; a0l.w += ma.w * e0;
        a0h.x += mb.x * e0; a0h.y += mb.y * e0; a0h.z += mb.z * e0; a0h.w += mb.w * e0;
        a1l.x += ma.x * e1; a1l.y += ma.y * e1; a1l.z += ma.z * e1; a1l.w += ma.w * e1;
        a1h.x += mb.x * e1; a1h.y += mb.y * e1; a1h.z += mb.z * e1; a1h.w += mb.w * e1;
    }

    uint4 u0, u1;
    u0.x = pk2bf(a0l.x, a0l.y); u0.y = pk2bf(a0l.z, a0l.w);
    u0.z = pk2bf(a0h.x, a0h.y); u0.w = pk2bf(a0h.z, a0h.w);
    u1.x = pk2bf(a1l.x, a1l.y); u1.y = pk2bf(a1l.z, a1l.w);
    u1.z = pk2bf(a1h.x, a1h.y); u1.w = pk2bf(a1h.z, a1h.w);
    *(uint4*)(Apre + (size_t)v * 512 + c8)       = u0;
    *(uint4*)(Apre + (size_t)v * 512 + 256 + c8) = u1;

    // xbf (self-loop A operand; loop_rel folded into WcT)
    const float* xv = x + (size_t)v * IN_C + c8;
    float4 xl = *(const float4*)xv, xh = *(const float4*)(xv + 4);
    uint4 ux;
    ux.x = pk2bf(xl.x, xl.y); ux.y = pk2bf(xl.z, xl.w);
    ux.z = pk2bf(xh.x, xh.y); ux.w = pk2bf(xh.z, xh.w);
    *(uint4*)(outu + (size_t)(v >> 7) * 65536 + (size_t)(v & 127) * 256 + c8) = ux;
}

// ---------------- fused GEMM, 2-deep counted-vmcnt pipeline ----------------
// out_h(bf16, into Apre rows) = [Apre | xbf] @ WcT^T, /3 + bias; BN col partials.
// 128 rows x 256 cols per block, 8 waves (2x4). K=768, BK=64, 12 steps.
// LDS: A dbuf 2x16KB @0, B dbuf 2x32KB @32768 (96KB). Epilogue reuses LDS.
__global__ __launch_bounds__(512)
void mfma_gemm(unsigned short* Ap /* Apre, also h output */,
               const unsigned short* __restrict__ xbf,
               const unsigned short* __restrict__ WcT,
               const float* __restrict__ bias, float* __restrict__ partial) {
    __shared__ __align__(16) unsigned char smem[98304];

    const int t    = threadIdx.x;
    const int m0   = blockIdx.x * 128;
    const int wid  = t >> 6;
    const int lane = t & 63;
    const int wm   = wid >> 2;
    const int wn   = wid & 3;
    const int lr   = lane & 15;
    const int qk   = lane >> 4;
    const int sxr  = lr & 7;
    const int wbase = t & 0x1C0;

    // staging constants
    int arow[2], acsw[2], brow[4], bcsw[4];
    #pragma unroll
    for (int j = 0; j < 2; ++j) {
        int g = j * 512 + t;
        arow[j] = g >> 3;
        acsw[j] = (g & 7) ^ (arow[j] & 7);
    }
    #pragma unroll
    for (int j = 0; j < 4; ++j) {
        int g = j * 512 + t;
        brow[j] = g >> 3;
        bcsw[j] = (g & 7) ^ (brow[j] & 7);
    }

    auto A_lds = [&](int buf) { return (unsigned short*)(smem + buf * 16384); };
    auto B_lds = [&](int buf) { return (unsigned short*)(smem + 32768 + buf * 32768); };

    auto stage = [&](int buf, int ks) {
        #pragma unroll
        for (int j = 0; j < 2; ++j) {
            int rg = m0 + arow[j];
            if (rg >= V_N) rg = V_N - 1;
            const unsigned short* s = (ks < 8)
                ? Ap  + (size_t)rg * 512 + ks * 64 + acsw[j] * 8
                : xbf + (size_t)blockIdx.x * 65536 + (size_t)(rg - m0) * 256 + (ks - 8) * 64 + acsw[j] * 8;
            gload16(s, A_lds(buf) + (size_t)(j * 512 + wbase) * 8);
        }
        #pragma unroll
        for (int j = 0; j < 4; ++j) {
            const unsigned short* s = WcT + (size_t)brow[j] * 768 + ks * 64 + bcsw[j] * 8;
            gload16(s, B_lds(buf) + (size_t)(j * 512 + wbase) * 8);
        }
    };

    f32x4 acc[4][4];
    #pragma unroll
    for (int m = 0; m < 4; m++)
        #pragma unroll
        for (int n = 0; n < 4; n++)
            acc[m][n] = (f32x4){0.f, 0.f, 0.f, 0.f};

    stage(0, 0);
    stage(1, 1);

    #pragma unroll
    for (int ks = 0; ks < 12; ++ks) {
        const int buf = ks & 1;
        if (ks < 11) { asm volatile("s_waitcnt vmcnt(6)" ::: "memory"); }
        else         { asm volatile("s_waitcnt vmcnt(0)" ::: "memory"); }
        __builtin_amdgcn_s_barrier();
        __builtin_amdgcn_sched_barrier(0);
        const unsigned short* Ab = A_lds(buf);
        const unsigned short* Bb = B_lds(buf);
        #pragma unroll
        for (int h = 0; h < 2; ++h) {
            short8 av[4], bv[4];
            #pragma unroll
            for (int m = 0; m < 4; m++)
                av[m] = *(const short8*)&Ab[(size_t)((wm * 64 + m * 16 + lr) * 8 + ((h * 4 + qk) ^ sxr)) * 8];
            #pragma unroll
            for (int n = 0; n < 4; n++)
                bv[n] = *(const short8*)&Bb[(size_t)((wn * 64 + n * 16 + lr) * 8 + ((h * 4 + qk) ^ sxr)) * 8];
            #pragma unroll
            for (int m = 0; m < 4; m++)
                #pragma unroll
                for (int n = 0; n < 4; n++)
                    acc[m][n] = __builtin_amdgcn_mfma_f32_16x16x32_bf16(av[m], bv[n], acc[m][n], 0, 0, 0);
        }
        __builtin_amdgcn_sched_barrier(0);
        __builtin_amdgcn_s_barrier();
        __builtin_amdgcn_sched_barrier(0);
        if (ks + 2 < 12) stage(buf, ks + 2);
    }

    // ---- epilogue: h = acc/3 + bias (bf16), LDS-staged coalesced store, BN partials ----
    unsigned short* Cst = (unsigned short*)smem;     // [64][264] ushort = 33792 B
    float* bs = (float*)(smem + 34816);              // 512 floats
    bs[t] = 0.f;
    __syncthreads();

    const float inv3 = 1.f / 3.f;
    float bco[4];
    #pragma unroll
    for (int n = 0; n < 4; n++) bco[n] = bias[wn * 64 + n * 16 + lr];

    float s[4]  = {0.f, 0.f, 0.f, 0.f};
    float s2[4] = {0.f, 0.f, 0.f, 0.f};

    #pragma unroll
    for (int p = 0; p < 2; ++p) {
        if (wm == p) {
            #pragma unroll
            for (int m = 0; m < 4; m++) {
                #pragma unroll
                for (int n = 0; n < 4; n++) {
                    const int col = wn * 64 + n * 16 + lr;
                    #pragma unroll
                    for (int j = 0; j < 4; j++) {
                        int rl = m * 16 + qk * 4 + j;
                        float h = acc[m][n][j] * inv3 + bco[n];
                        if (m0 + p * 64 + rl < V_N) { s[n] += h; s2[n] += h * h; }
                        Cst[rl * 264 + col] = f2bf(h);
                    }
                }
            }
        }
        __syncthreads();
        #pragma unroll
        for (int i = 0; i < 4; ++i) {
            int f = t + i * 512;            // 0..2047 chunks of 8 ushorts
            int row = f >> 5;
            int c8  = (f & 31) * 8;
            int r = m0 + p * 64 + row;
            if (r < V_N) {
                uint4 val = *(const uint4*)&Cst[row * 264 + c8];
                *(uint4*)&Ap[(size_t)r * 512 + c8] = val;
            }
        }
        __syncthreads();
    }

    #pragma unroll
    for (int n = 0; n < 4; n++) {
        s[n]  += __shfl_xor(s[n], 16);  s[n]  += __shfl_xor(s[n], 32);
        s2[n] += __shfl_xor(s2[n], 16); s2[n] += __shfl_xor(s2[n], 32);
    }
    if (lane < 16) {
        #pragma unroll
        for (int n = 0; n < 4; n++) {
            const int col = wn * 64 + n * 16 + lr;
            atomicAdd(&bs[col], s[n]);
            atomicAdd(&bs[256 + col], s2[n]);
        }
    }
    __syncthreads();
    partial[(size_t)blockIdx.x * 512 + t] = bs[t];
}

// ---------------- BN reduce + finalize + normalize ----------------

__global__ void bn_reduce_part(const float* __restrict__ partial, float* __restrict__ sums) {
    int t = threadIdx.x;                       // 512
    int b0 = blockIdx.x * 196;
    int b1 = b0 + 196; if (b1 > MTILES) b1 = MTILES;
    float S = 0.f;
    for (int b = b0; b < b1; b++) S += partial[(size_t)b * 512 + t];
    atomicAdd(&sums[t], S);
}

__global__ void bn_finalize(const float* __restrict__ sums, float* __restrict__ ms) {
    int c = threadIdx.x;                       // 256
    float mean = sums[c] / (float)V_N;
    float var  = sums[256 + c] / (float)V_N - mean * mean;
    ms[c]       = mean;
    ms[256 + c] = rsqrtf(var + BN_EPS);
}

// read h (bf16, Apre rows), write normalized f32 out
__global__ void bn_norm2(const unsigned short* __restrict__ hbf,
                         const float* __restrict__ ms, float* __restrict__ out) {
    const size_t total8 = (size_t)V_N * 32;    // chunks of 8 elems
    size_t stride = (size_t)gridDim.x * blockDim.x;
    for (size_t idx = (size_t)blockIdx.x * blockDim.x + threadIdx.x; idx < total8; idx += stride) {
        size_t v  = idx >> 5;
        int   c8  = (int)(idx & 31) * 8;
        uint4 uv = *(const uint4*)&hbf[v * 512 + c8];
        float4 ma = *(const float4*)&ms[c8];
        float4 mb = *(const float4*)&ms[c8 + 4];
        float4 ra = *(const float4*)&ms[256 + c8];
        float4 rb = *(const float4*)&ms[256 + c8 + 4];
        unsigned int w0 = uv.x, w1 = uv.y, w2 = uv.z, w3 = uv.w;
        float4 h0, h1;
        h0.x = (__builtin_bit_cast(float, (w0 << 16))        - ma.x) * ra.x;
        h0.y = (__builtin_bit_cast(float, (w0 & 0xFFFF0000u)) - ma.y) * ra.y;
        h0.z = (__builtin_bit_cast(float, (w1 << 16))        - ma.z) * ra.z;
        h0.w = (__builtin_bit_cast(float, (w1 & 0xFFFF0000u)) - ma.w) * ra.w;
        h1.x = (__builtin_bit_cast(float, (w2 << 16))        - mb.x) * rb.x;
        h1.y = (__builtin_bit_cast(float, (w2 & 0xFFFF0000u)) - mb.y) * rb.y;
        h1.z = (__builtin_bit_cast(float, (w3 << 16))        - mb.z) * rb.z;
        h1.w = (__builtin_bit_cast(float, (w3 & 0xFFFF0000u)) - mb.w) * rb.w;
        float* o = out + v * 256 + c8;
        *(float4*)o       = h0;
        *(float4*)(o + 4) = h1;
    }
}

__global__ void rel_out_kernel(const float* __restrict__ rel_repr,
                               const float* __restrict__ loop_rel,
                               const float* __restrict__ w_rel,
                               float* __restrict__ out)
{
    int r = blockIdx.x;
    const float* row = (r < NREL2) ? (rel_repr + (size_t)r * IN_C) : loop_rel;
    int l = threadIdx.x;
    float s = 0.f;
    #pragma unroll
    for (int q = 0; q < 4; q++) {
        int k = l + q * 64;
        s += row[k] * w_rel[(size_t)k * OUT_C + (OUT_C - 1)];
    }
    #pragma unroll
    for (int m = 32; m >= 1; m >>= 1) s += __shfl_xor(s, m);
    if (l == 0) out[(size_t)V_N * OUT_C + r] = s;
}

// ---------------- launch ----------------

extern "C" void kernel_launch(void* const* d_in, const int* in_sizes, int n_in,
                              void* d_out, int out_size, void* d_ws, size_t ws_size,
                              hipStream_t stream) {
    const float* x        = (const float*)d_in[0];
    const float* rel_repr = (const float*)d_in[1];
    const float* w        = (const float*)d_in[2];
    const float* w_rel    = (const float*)d_in[3];
    const float* loop_rel = (const float*)d_in[4];
    const float* bias     = (const float*)d_in[5];
    const int*   src      = (const int*)d_in[6];
    const int*   dst      = (const int*)d_in[7];
    const int*   etype    = (const int*)d_in[8];
    const int*   edir     = (const int*)d_in[9];
    float* out = (float*)d_out;
    unsigned short* outu = (unsigned short*)d_out;

    // workspace layout (105.60 MB, within round-2-proven bound)
    char* wsb = (char*)d_ws;
    int*   cnt     = (int*)(wsb + 0);              // 400,000
    int*   cursor  = (int*)(wsb + 400000);         // 400,000
    int*   offs    = (int*)(wsb + 800000);         // 400,000
    float* degi    = (float*)(wsb + 1200000);      // 400,000
    int*   bsum    = (int*)(wsb + 1600000);        // 392
    float* partial = (float*)(wsb + 0);            // alias region0 (1,601,536 < 1,601,792)
    int*   epack   = (int*)(wsb + 1601792);        // 1,200,000
    float* ms      = (float*)(wsb + 2801792);      // 2048
    float* sums    = (float*)(wsb + 2803840);      // 2048
    unsigned short* WcT  = (unsigned short*)(wsb + 2805888);   // 393,216
    unsigned short* Apre = (unsigned short*)(wsb + 3199104);   // 102,400,000

    hipMemsetAsync(wsb, 0, 800000, stream);        // cnt + cursor
    hipMemsetAsync(sums, 0, 2048, stream);

    count_kernel<<<(E_N + 255) / 256, 256, 0, stream>>>(dst, cnt);
    scan1<<<NB_SCAN, 1024, 0, stream>>>(cnt, bsum, degi);
    scan2<<<1, 128, 0, stream>>>(bsum);
    scan3<<<NB_SCAN, 1024, 0, stream>>>(cnt, bsum, offs);
    scatter_kernel<<<(E_N + 255) / 256, 256, 0, stream>>>(dst, src, etype, edir,
                                                          offs, cursor, epack);
    convert_w<<<768, 256, 0, stream>>>(w, loop_rel, WcT);
    aggregate<<<(V_N * 32 + 255) / 256, 256, 0, stream>>>(x, rel_repr, degi, cnt, offs,
                                                          epack, Apre, outu);
    mfma_gemm<<<MTILES, 512, 0, stream>>>(Apre, outu, WcT, bias, partial);
    bn_reduce_part<<<4, 512, 0, stream>>>(partial, sums);
    bn_finalize<<<1, 256, 0, stream>>>(sums, ms);
    bn_norm2<<<2048, 256, 0, stream>>>(Apre, ms, out);
    rel_out_kernel<<<NREL2 + 1, 64, 0, stream>>>(rel_repr, loop_rel, w_rel, out);
}